// Round 3
// baseline (1060.404 us; speedup 1.0000x reference)
//
#include <hip/hip_runtime.h>
#include <stdint.h>

#define B_ROWS 32768
#define K_CENT 4096
#define D_DIM  1024
#define EPS_CAND 5e-4f

typedef unsigned short u16;
typedef __attribute__((ext_vector_type(8))) __bf16 bf16x8;
typedef __attribute__((ext_vector_type(4))) float f32x4;

__device__ inline u16 f32_to_bf16(float f) {
    unsigned u = __float_as_uint(f);
    u += 0x7FFFu + ((u >> 16) & 1u);   // round-to-nearest-even
    return (u16)(u >> 16);
}
__device__ inline float bf16_to_f32(u16 h) {
    return __uint_as_float(((unsigned)h) << 16);
}
// order-preserving f32 -> u32 (works for all finite values)
__device__ inline unsigned ord_of_f32(float f) {
    unsigned u = __float_as_uint(f);
    return (u & 0x80000000u) ? ~u : (u | 0x80000000u);
}
__device__ inline float f32_of_ord(unsigned o) {
    unsigned u = (o & 0x80000000u) ? (o & 0x7fffffffu) : ~o;
    return __uint_as_float(u);
}

// ---------------------------------------------------------------------------
// prep_rows: one block per row (verified round 2, unchanged).
// ---------------------------------------------------------------------------
__global__ __launch_bounds__(256) void prep_rows(
    const float* __restrict__ src, u16* __restrict__ hi, u16* __restrict__ lo,
    float* __restrict__ sq, float* __restrict__ den)
{
    __shared__ double sm[4];
    const int row = blockIdx.x, tid = threadIdx.x;
    const float4 v = reinterpret_cast<const float4*>(src + (size_t)row * D_DIM)[tid];
    double ss = (double)v.x * v.x + (double)v.y * v.y
              + (double)v.z * v.z + (double)v.w * v.w;
#pragma unroll
    for (int m = 1; m < 64; m <<= 1) ss += __shfl_xor(ss, m, 64);
    if ((tid & 63) == 0) sm[tid >> 6] = ss;
    __syncthreads();
    const double tot = sm[0] + sm[1] + sm[2] + sm[3];
    const float d = fmaxf(sqrtf((float)tot), 1e-12f);
    const float n0 = v.x / d, n1 = v.y / d, n2 = v.z / d, n3 = v.w / d;

    ushort4 h, l;
    h.x = f32_to_bf16(n0); l.x = f32_to_bf16(n0 - bf16_to_f32(h.x));
    h.y = f32_to_bf16(n1); l.y = f32_to_bf16(n1 - bf16_to_f32(h.y));
    h.z = f32_to_bf16(n2); l.z = f32_to_bf16(n2 - bf16_to_f32(h.z));
    h.w = f32_to_bf16(n3); l.w = f32_to_bf16(n3 - bf16_to_f32(h.w));
    reinterpret_cast<ushort4*>(hi + (size_t)row * D_DIM)[tid] = h;
    reinterpret_cast<ushort4*>(lo + (size_t)row * D_DIM)[tid] = l;

    double s2 = (double)n0 * n0 + (double)n1 * n1
              + (double)n2 * n2 + (double)n3 * n3;
#pragma unroll
    for (int m = 1; m < 64; m <<= 1) s2 += __shfl_xor(s2, m, 64);
    __syncthreads();
    if ((tid & 63) == 0) sm[tid >> 6] = s2;
    __syncthreads();
    if (tid == 0) {
        sq[row] = (float)(sm[0] + sm[1] + sm[2] + sm[3]);
        den[row] = d;
    }
}

// ---------------------------------------------------------------------------
// gemm_cand: bf16x3 emulated Xhat.Chat^T + fused per-(row, 64-col-group)
// packed argmin candidates. NEW this round: 256x128 tile, BK=32, 8 waves
// (4M x 2N), TRIPLE-buffered LDS (3 x 48 KB) with 2-tiles-ahead prefetch and
// counted s_waitcnt vmcnt(6) at tile boundaries (T3+T4), raw s_barrier
// phases with setprio(1) around MFMA clusters (T5). Numeric path identical
// to the verified round-2 kernel.
// ---------------------------------------------------------------------------
#define BM 256
#define BN 128
#define BK 32
#define NT (D_DIM / BK)      // 32
#define REG_U16 4096         // one 8 KB staging region, in u16 units
#define TILE_U16 (6 * REG_U16)  // 48 KB: Ahi(2 regions) Alo(2) Bhi(1) Blo(1)

__global__ __launch_bounds__(512, 2) void gemm_cand(
    const u16* __restrict__ Ahi, const u16* __restrict__ Alo,
    const u16* __restrict__ Bhi, const u16* __restrict__ Blo,
    const float* __restrict__ c2, unsigned long long* __restrict__ cand)
{
    __shared__ u16 lds[3 * TILE_U16];   // 144 KiB

    const int tid = threadIdx.x, lane = tid & 63, w = tid >> 6;
    const int wm = w >> 1, wn = w & 1;
    const int fr = lane & 15, fc = lane >> 4;

    // bijective XCD swizzle (4096 = 8 x 512) + serpentine colblock
    const int flat = blockIdx.x;
    const int swz = (flat & 7) * 512 + (flat >> 3);
    int bx = swz & 31;                  // colblock 0..31
    const int by = swz >> 5;            // rowblock 0..127
    if (by & 1) bx = 31 - bx;
    const size_t arow0 = (size_t)by * BM;
    const size_t brow0 = (size_t)bx * BN;

    // staging: per 8KB region, chunk p = w*64+lane; row=p>>2,
    // chunkcol=(p&3)^((row>>1)&3)  (involution pre-applied to global src;
    // LDS dest linear per global_load_lds requirement).
    const int p = w * 64 + lane;
    const int srow = p >> 2;
    const int scc = (p & 3) ^ ((srow >> 1) & 3);
    const u16* gsrc[6];
    gsrc[0] = Ahi + (arow0 + srow) * D_DIM + scc * 8;
    gsrc[1] = Ahi + (arow0 + 128 + srow) * D_DIM + scc * 8;
    gsrc[2] = Alo + (arow0 + srow) * D_DIM + scc * 8;
    gsrc[3] = Alo + (arow0 + 128 + srow) * D_DIM + scc * 8;
    gsrc[4] = Bhi + (brow0 + srow) * D_DIM + scc * 8;
    gsrc[5] = Blo + (brow0 + srow) * D_DIM + scc * 8;
    const int ldw = w * 512;            // per-wave u16 offset inside a region

    // fragment ds_read offsets (u16, buffer-relative, kt-invariant)
    int offA[4], offB[4];
#pragma unroll
    for (int i = 0; i < 4; ++i) {
        const int ar = wm * 64 + i * 16 + fr;          // 0..255
        const int rg = ar >> 7, rr = ar & 127;
        offA[i] = rg * REG_U16 + rr * 32 + ((fc ^ ((rr >> 1) & 3)) * 8);
        const int br = wn * 64 + i * 16 + fr;          // 0..127
        offB[i] = br * 32 + ((fc ^ ((br >> 1) & 3)) * 8);
    }

    f32x4 acc[4][4] = {};

    // stage 3 regions [J0, J0+3) of tile t into buffer t%3
#define STAGE3(t, J0)                                                         \
    do {                                                                      \
        const int _base = ((t) % 3) * TILE_U16;                               \
        const int _k = (t) * BK;                                              \
        _Pragma("unroll")                                                     \
        for (int _j = (J0); _j < (J0) + 3; ++_j)                              \
            __builtin_amdgcn_global_load_lds(                                 \
                (const __attribute__((address_space(1))) void*)(gsrc[_j] + _k), \
                (__attribute__((address_space(3))) void*)(lds + _base + _j * REG_U16 + ldw), \
                16, 0, 0);                                                    \
    } while (0)

    // prologue: tiles 0 and 1 fully staged; wait tile 0 (6 newest in flight)
    STAGE3(0, 0); STAGE3(0, 3);
    STAGE3(1, 0); STAGE3(1, 3);
    asm volatile("s_waitcnt vmcnt(6)" ::: "memory");
    __builtin_amdgcn_s_barrier();

    for (int t = 0; t < NT; ++t) {
        const int cb = (t % 3) * TILE_U16;

        // ---- phase 0: B (all 8 frags) + A m-half 0; prefetch half of t+2
        bf16x8 bhf[4], blf[4], ah0[2], al0[2];
#pragma unroll
        for (int n = 0; n < 4; ++n) {
            bhf[n] = *reinterpret_cast<const bf16x8*>(lds + cb + 4 * REG_U16 + offB[n]);
            blf[n] = *reinterpret_cast<const bf16x8*>(lds + cb + 5 * REG_U16 + offB[n]);
        }
#pragma unroll
        for (int i = 0; i < 2; ++i) {
            ah0[i] = *reinterpret_cast<const bf16x8*>(lds + cb + offA[i]);
            al0[i] = *reinterpret_cast<const bf16x8*>(lds + cb + 2 * REG_U16 + offA[i]);
        }
        if (t + 2 < NT) STAGE3(t + 2, 0);
        __builtin_amdgcn_sched_barrier(0);
        __builtin_amdgcn_s_barrier();
        __builtin_amdgcn_s_setprio(1);
#pragma unroll
        for (int i = 0; i < 2; ++i)
#pragma unroll
            for (int n = 0; n < 4; ++n)
                acc[i][n] = __builtin_amdgcn_mfma_f32_16x16x32_bf16(ah0[i], bhf[n], acc[i][n], 0, 0, 0);
#pragma unroll
        for (int i = 0; i < 2; ++i)
#pragma unroll
            for (int n = 0; n < 4; ++n)
                acc[i][n] = __builtin_amdgcn_mfma_f32_16x16x32_bf16(ah0[i], blf[n], acc[i][n], 0, 0, 0);
#pragma unroll
        for (int i = 0; i < 2; ++i)
#pragma unroll
            for (int n = 0; n < 4; ++n)
                acc[i][n] = __builtin_amdgcn_mfma_f32_16x16x32_bf16(al0[i], bhf[n], acc[i][n], 0, 0, 0);
        __builtin_amdgcn_s_setprio(0);
        __builtin_amdgcn_s_barrier();

        // ---- phase 1: A m-half 1; prefetch rest of t+2
        bf16x8 ah1[2], al1[2];
#pragma unroll
        for (int i = 0; i < 2; ++i) {
            ah1[i] = *reinterpret_cast<const bf16x8*>(lds + cb + offA[2 + i]);
            al1[i] = *reinterpret_cast<const bf16x8*>(lds + cb + 2 * REG_U16 + offA[2 + i]);
        }
        if (t + 2 < NT) STAGE3(t + 2, 3);
        __builtin_amdgcn_sched_barrier(0);
        __builtin_amdgcn_s_barrier();
        __builtin_amdgcn_s_setprio(1);
#pragma unroll
        for (int i = 0; i < 2; ++i)
#pragma unroll
            for (int n = 0; n < 4; ++n)
                acc[2 + i][n] = __builtin_amdgcn_mfma_f32_16x16x32_bf16(ah1[i], bhf[n], acc[2 + i][n], 0, 0, 0);
#pragma unroll
        for (int i = 0; i < 2; ++i)
#pragma unroll
            for (int n = 0; n < 4; ++n)
                acc[2 + i][n] = __builtin_amdgcn_mfma_f32_16x16x32_bf16(ah1[i], blf[n], acc[2 + i][n], 0, 0, 0);
#pragma unroll
        for (int i = 0; i < 2; ++i)
#pragma unroll
            for (int n = 0; n < 4; ++n)
                acc[2 + i][n] = __builtin_amdgcn_mfma_f32_16x16x32_bf16(al1[i], bhf[n], acc[2 + i][n], 0, 0, 0);
        __builtin_amdgcn_s_setprio(0);

        // tile boundary: counted wait (tile t+1 ready; t+2's 6 stay in flight)
        if (t < NT - 2)       asm volatile("s_waitcnt vmcnt(6)" ::: "memory");
        else if (t == NT - 2) asm volatile("s_waitcnt vmcnt(0)" ::: "memory");
        if (t < NT - 1) __builtin_amdgcn_s_barrier();
    }
#undef STAGE3

    // epilogue: per-row min over this wave's 64 columns -> cand[row][group]
    const int group = bx * 2 + wn;
    float c2v[4];
#pragma unroll
    for (int n = 0; n < 4; ++n)
        c2v[n] = c2[brow0 + wn * 64 + n * 16 + fr];

#pragma unroll
    for (int mi = 0; mi < 4; ++mi) {
#pragma unroll
        for (int r = 0; r < 4; ++r) {
            unsigned long long bk = ~0ull;
#pragma unroll
            for (int ni = 0; ni < 4; ++ni) {
                const float d2a = c2v[ni] - 2.0f * acc[mi][ni][r];
                const unsigned col = (unsigned)(brow0 + wn * 64 + ni * 16 + fr);
                const unsigned long long key =
                    ((unsigned long long)ord_of_f32(d2a) << 32) | col;
                if (key < bk) bk = key;
            }
#pragma unroll
            for (int ms = 1; ms < 16; ms <<= 1) {
                const unsigned long long o = __shfl_xor(bk, ms, 64);
                if (o < bk) bk = o;
            }
            if (fr == 0) {
                const size_t grow = arow0 + wm * 64 + mi * 16 + fc * 4 + r;
                cand[grow * 64 + group] = bk;
            }
        }
    }
}

// ---------------------------------------------------------------------------
// finalize: verified round 2, unchanged.
// ---------------------------------------------------------------------------
__global__ __launch_bounds__(256) void finalize(
    const unsigned long long* __restrict__ cand,
    const float* __restrict__ X, const float* __restrict__ C,
    const float* __restrict__ denx, const float* __restrict__ denc,
    const float* __restrict__ x2, const float* __restrict__ c2,
    float* __restrict__ out)
{
    const int w = threadIdx.x >> 6, lane = threadIdx.x & 63;
    const size_t row = (size_t)blockIdx.x * 4 + w;

    const unsigned long long v = cand[row * 64 + lane];
    unsigned long long m = v;
#pragma unroll
    for (int ms = 1; ms < 64; ms <<= 1) {
        const unsigned long long o = __shfl_xor(m, ms, 64);
        if (o < m) m = o;
    }
    const float fmin = f32_of_ord((unsigned)(m >> 32));
    const bool is_cand = f32_of_ord((unsigned)(v >> 32)) <= fmin + EPS_CAND;
    const unsigned long long ball = __ballot(is_cand);

    unsigned win;
    if (__popcll(ball) == 1) {
        win = (unsigned)(m & 0xffffffffu);
    } else {
        const float dxr = denx[row];
        const float x2r = x2[row];
        float xv[16];
#pragma unroll
        for (int j = 0; j < 16; ++j)
            xv[j] = X[row * D_DIM + j * 64 + lane] / dxr;

        float bestd2 = __uint_as_float(0x7f800000u);
        unsigned bwin = 0xffffffffu;
        unsigned long long bb = ball;
        while (bb) {
            const int l = __ffsll((unsigned long long)bb) - 1;
            bb &= bb - 1;
            const unsigned col = (unsigned)(__shfl(v, l, 64) & 0xffffffffu);
            const float dcr = denc[col];
            double s = 0.0;
#pragma unroll
            for (int j = 0; j < 16; ++j) {
                const float cv = C[(size_t)col * D_DIM + j * 64 + lane] / dcr;
                s = fma((double)xv[j], (double)cv, s);
            }
#pragma unroll
            for (int ms = 1; ms < 64; ms <<= 1) s += __shfl_xor(s, ms, 64);
            const float dotf = (float)s;
            const float d2 = (x2r + c2[col]) - 2.0f * dotf;
            if (d2 < bestd2 || (d2 == bestd2 && col < bwin)) {
                bestd2 = d2; bwin = col;
            }
        }
        win = bwin;
    }

    const float4* s4 = reinterpret_cast<const float4*>(C + (size_t)win * D_DIM);
    float4* d4 = reinterpret_cast<float4*>(out + row * D_DIM);
#pragma unroll
    for (int t = 0; t < 4; ++t) d4[t * 64 + lane] = s4[t * 64 + lane];
}

extern "C" void kernel_launch(void* const* d_in, const int* in_sizes, int n_in,
                              void* d_out, int out_size, void* d_ws, size_t ws_size,
                              hipStream_t stream)
{
    (void)in_sizes; (void)n_in; (void)out_size; (void)ws_size;
    const float* X = (const float*)d_in[0];   // [32768,1024] f32
    const float* C = (const float*)d_in[1];   // [4096,1024]  f32
    float* out = (float*)d_out;               // [32768,1024] f32

    char* ws = (char*)d_ws;
    u16* Ahi = (u16*)ws;                                     // 64 MiB
    u16* Alo = Ahi + (size_t)B_ROWS * D_DIM;                 // 64 MiB
    u16* Bhi = Alo + (size_t)B_ROWS * D_DIM;                 //  8 MiB
    u16* Blo = Bhi + (size_t)K_CENT * D_DIM;                 //  8 MiB
    unsigned long long* cand =
        (unsigned long long*)(Blo + (size_t)K_CENT * D_DIM); // 16 MiB
    float* c2   = (float*)(cand + (size_t)B_ROWS * 64);      // 16 KiB
    float* x2   = c2 + K_CENT;                               // 128 KiB
    float* denx = x2 + B_ROWS;                               // 128 KiB
    float* denc = denx + B_ROWS;                             // 16 KiB

    prep_rows<<<B_ROWS, 256, 0, stream>>>(X, Ahi, Alo, x2, denx);
    prep_rows<<<K_CENT, 256, 0, stream>>>(C, Bhi, Blo, c2, denc);
    gemm_cand<<<(B_ROWS / BM) * (K_CENT / BN), 512, 0, stream>>>(
        Ahi, Alo, Bhi, Blo, c2, cand);
    finalize<<<B_ROWS / 4, 256, 0, stream>>>(
        cand, X, C, denx, denc, x2, c2, out);
}

// Round 4
// 990.810 us; speedup vs baseline: 1.0702x; 1.0702x over previous
//
#include <hip/hip_runtime.h>
#include <stdint.h>

#define B_ROWS 32768
#define K_CENT 4096
#define D_DIM  1024
#define EPS_CAND 5e-4f

typedef unsigned short u16;
typedef __attribute__((ext_vector_type(8))) __bf16 bf16x8;
typedef __attribute__((ext_vector_type(4))) float f32x4;

__device__ inline u16 f32_to_bf16(float f) {
    unsigned u = __float_as_uint(f);
    u += 0x7FFFu + ((u >> 16) & 1u);   // round-to-nearest-even
    return (u16)(u >> 16);
}
__device__ inline float bf16_to_f32(u16 h) {
    return __uint_as_float(((unsigned)h) << 16);
}
__device__ inline unsigned ord_of_f32(float f) {
    unsigned u = __float_as_uint(f);
    return (u & 0x80000000u) ? ~u : (u | 0x80000000u);
}
__device__ inline float f32_of_ord(unsigned o) {
    unsigned u = (o & 0x80000000u) ? (o & 0x7fffffffu) : ~o;
    return __uint_as_float(u);
}
__device__ inline void gload_lds16(const u16* g, u16* l) {
    __builtin_amdgcn_global_load_lds(
        (const __attribute__((address_space(1))) void*)g,
        (__attribute__((address_space(3))) void*)l, 16, 0, 0);
}

// ---------------------------------------------------------------------------
// prep_rows: verified rounds 2-3, unchanged.
// ---------------------------------------------------------------------------
__global__ __launch_bounds__(256) void prep_rows(
    const float* __restrict__ src, u16* __restrict__ hi, u16* __restrict__ lo,
    float* __restrict__ sq, float* __restrict__ den)
{
    __shared__ double sm[4];
    const int row = blockIdx.x, tid = threadIdx.x;
    const float4 v = reinterpret_cast<const float4*>(src + (size_t)row * D_DIM)[tid];
    double ss = (double)v.x * v.x + (double)v.y * v.y
              + (double)v.z * v.z + (double)v.w * v.w;
#pragma unroll
    for (int m = 1; m < 64; m <<= 1) ss += __shfl_xor(ss, m, 64);
    if ((tid & 63) == 0) sm[tid >> 6] = ss;
    __syncthreads();
    const double tot = sm[0] + sm[1] + sm[2] + sm[3];
    const float d = fmaxf(sqrtf((float)tot), 1e-12f);
    const float n0 = v.x / d, n1 = v.y / d, n2 = v.z / d, n3 = v.w / d;

    ushort4 h, l;
    h.x = f32_to_bf16(n0); l.x = f32_to_bf16(n0 - bf16_to_f32(h.x));
    h.y = f32_to_bf16(n1); l.y = f32_to_bf16(n1 - bf16_to_f32(h.y));
    h.z = f32_to_bf16(n2); l.z = f32_to_bf16(n2 - bf16_to_f32(h.z));
    h.w = f32_to_bf16(n3); l.w = f32_to_bf16(n3 - bf16_to_f32(h.w));
    reinterpret_cast<ushort4*>(hi + (size_t)row * D_DIM)[tid] = h;
    reinterpret_cast<ushort4*>(lo + (size_t)row * D_DIM)[tid] = l;

    double s2 = (double)n0 * n0 + (double)n1 * n1
              + (double)n2 * n2 + (double)n3 * n3;
#pragma unroll
    for (int m = 1; m < 64; m <<= 1) s2 += __shfl_xor(s2, m, 64);
    __syncthreads();
    if ((tid & 63) == 0) sm[tid >> 6] = s2;
    __syncthreads();
    if (tid == 0) {
        sq[row] = (float)(sm[0] + sm[1] + sm[2] + sm[3]);
        den[row] = d;
    }
}

// ---------------------------------------------------------------------------
// gemm_cand: bf16x3 via K-augmentation -> ONE standard GEMM, K' = 3072:
//   tiles  0..15: Ahi x Bhi   (k = 16*t .. )
//   tiles 16..31: Alo x Bhi
//   tiles 32..47: Ahi x Blo
// m201 8-phase template: BM=BN=256, BK=64, 8 waves (2M x 4N), double-buffered
// 128 KB LDS in k-half regions (16 KB each: 256 rows x 32 k), 4 phases/tile
// {ds_read 4-8 x b128; 1 half stage (2 gloads); barrier; setprio(1); 16 MFMA;
// setprio(0); barrier}, counted vmcnt(4) twice per tile (never 0 mid-loop).
// Epilogue: per-(row, 64-col group) packed argmin candidates (unique writer).
// ---------------------------------------------------------------------------
#define BM 256
#define BN 256
#define BK 64
#define NT 48
#define AREG 8192        // one k-half region, u16 units (16 KiB)
#define BOFF_U16 16384   // B offset within a buffer, u16
#define BUF_U16 32768    // one buffer (A + B), u16 (64 KiB)

__global__ __launch_bounds__(512, 2) void gemm_cand(
    const u16* __restrict__ Ahi, const u16* __restrict__ Alo,
    const u16* __restrict__ Bhi, const u16* __restrict__ Blo,
    const float* __restrict__ c2, unsigned long long* __restrict__ cand)
{
    __shared__ u16 lds[2 * BUF_U16];   // 128 KiB

    const int tid = threadIdx.x, lane = tid & 63, w = tid >> 6;
    const int wm = w >> 2, wn = w & 3;          // 2M x 4N wave grid
    const int fr = lane & 15, fc = lane >> 4;

    // bijective XCD swizzle (2048 = 8 x 256) + serpentine colblock
    const int flat = blockIdx.x;
    const int swz = (flat & 7) * 256 + (flat >> 3);
    int bx = swz & 15;                 // colblock 0..15
    const int by = swz >> 4;           // rowblock 0..127
    if (by & 1) bx = 15 - bx;
    const size_t arow0 = (size_t)by * BM;
    const size_t brow0 = (size_t)bx * BN;

    // staging lane offsets: phys chunk p in {tid, tid+512}; prow = p>>2,
    // pch = p&3; logical chunk lc = pch ^ ((prow>>1)&3) (involution applied
    // to the GLOBAL source; LDS dest linear per global_load_lds requirement).
    const int prow = tid >> 2, pch = tid & 3;
    const int lc = pch ^ ((prow >> 1) & 3);     // same lc for prow+128
    const size_t lane0 = (size_t)prow * D_DIM + lc * 8;
    const size_t lane1 = (size_t)(prow + 128) * D_DIM + lc * 8;
    const int dst0 = tid * 8, dst1 = tid * 8 + 4096;   // u16 within region
    const size_t abase = arow0 * D_DIM;
    const size_t bbase = brow0 * D_DIM;

    // issue order per tile tn (staged during tile tn-1): A(kh0), B(kh0),
    // A(kh1), B(kh1) -- the vmcnt ledger below depends on this order.
#define STAGE_A(tn, jj) do {                                                  \
    const u16* s_ = ((((tn) >> 4) == 1) ? Alo : Ahi) + abase                  \
                    + ((size_t)((tn) & 15)) * BK + (jj) * 32;                 \
    u16* d_ = lds + ((tn) & 1) * BUF_U16 + (jj) * AREG;                       \
    gload_lds16(s_ + lane0, d_ + dst0);                                       \
    gload_lds16(s_ + lane1, d_ + dst1);                                       \
} while (0)
#define STAGE_B(tn, jj) do {                                                  \
    const u16* s_ = ((((tn) >> 4) == 2) ? Blo : Bhi) + bbase                  \
                    + ((size_t)((tn) & 15)) * BK + (jj) * 32;                 \
    u16* d_ = lds + ((tn) & 1) * BUF_U16 + BOFF_U16 + (jj) * AREG;            \
    gload_lds16(s_ + lane0, d_ + dst0);                                       \
    gload_lds16(s_ + lane1, d_ + dst1);                                       \
} while (0)

    // fragment ds_read offsets (u16, region-relative, tile-invariant)
    int offA[8], offB[4];
#pragma unroll
    for (int i = 0; i < 8; ++i) {
        const int r = wm * 128 + i * 16 + fr;
        offA[i] = r * 32 + ((fc ^ ((r >> 1) & 3)) * 8);
    }
#pragma unroll
    for (int n = 0; n < 4; ++n) {
        const int r = wn * 64 + n * 16 + fr;
        offB[n] = r * 32 + ((fc ^ ((r >> 1) & 3)) * 8);
    }

    f32x4 acc[8][4] = {};

    // prologue: tile 0 fully staged; wait its kh0 (kh1's 4 loads stay in flight)
    STAGE_A(0, 0); STAGE_B(0, 0); STAGE_A(0, 1); STAGE_B(0, 1);
    asm volatile("s_waitcnt vmcnt(4)" ::: "memory");
    __builtin_amdgcn_s_barrier();
    __builtin_amdgcn_sched_barrier(0);

    for (int t = 0; t < NT; ++t) {
        const int cb = (t & 1) * BUF_U16;
        const u16* LA = lds + cb;
        const u16* LB = lds + cb + BOFF_U16;
        const int tn = t + 1;
        const bool st = tn < NT;

        bf16x8 af[4], bfr[4];

        // ---- phase (kh0, mhalf0): 8 reads, stage A-kh0(t+1), 16 MFMA
#pragma unroll
        for (int n = 0; n < 4; ++n)
            bfr[n] = *reinterpret_cast<const bf16x8*>(LB + offB[n]);
#pragma unroll
        for (int i = 0; i < 4; ++i)
            af[i] = *reinterpret_cast<const bf16x8*>(LA + offA[i]);
        if (st) STAGE_A(tn, 0);
        __builtin_amdgcn_sched_barrier(0);
        __builtin_amdgcn_s_barrier();
        __builtin_amdgcn_sched_barrier(0);
        __builtin_amdgcn_s_setprio(1);
#pragma unroll
        for (int i = 0; i < 4; ++i)
#pragma unroll
            for (int n = 0; n < 4; ++n)
                acc[i][n] = __builtin_amdgcn_mfma_f32_16x16x32_bf16(af[i], bfr[n], acc[i][n], 0, 0, 0);
        __builtin_amdgcn_s_setprio(0);
        __builtin_amdgcn_sched_barrier(0);
        __builtin_amdgcn_s_barrier();
        __builtin_amdgcn_sched_barrier(0);

        // ---- phase (kh0, mhalf1): 4 reads, stage B-kh0(t+1), 16 MFMA, W1
#pragma unroll
        for (int i = 0; i < 4; ++i)
            af[i] = *reinterpret_cast<const bf16x8*>(LA + offA[4 + i]);
        if (st) STAGE_B(tn, 0);
        __builtin_amdgcn_sched_barrier(0);
        __builtin_amdgcn_s_barrier();
        __builtin_amdgcn_sched_barrier(0);
        __builtin_amdgcn_s_setprio(1);
#pragma unroll
        for (int i = 0; i < 4; ++i)
#pragma unroll
            for (int n = 0; n < 4; ++n)
                acc[4 + i][n] = __builtin_amdgcn_mfma_f32_16x16x32_bf16(af[i], bfr[n], acc[4 + i][n], 0, 0, 0);
        __builtin_amdgcn_s_setprio(0);
        // W1: need this tile's kh1 (newer in flight: A-kh0(t+1), B-kh0(t+1))
        if (t == NT - 1) asm volatile("s_waitcnt vmcnt(0)" ::: "memory");
        else             asm volatile("s_waitcnt vmcnt(4)" ::: "memory");
        __builtin_amdgcn_sched_barrier(0);
        __builtin_amdgcn_s_barrier();
        __builtin_amdgcn_sched_barrier(0);

        // ---- phase (kh1, mhalf0): 8 reads, stage A-kh1(t+1), 16 MFMA
#pragma unroll
        for (int n = 0; n < 4; ++n)
            bfr[n] = *reinterpret_cast<const bf16x8*>(LB + AREG + offB[n]);
#pragma unroll
        for (int i = 0; i < 4; ++i)
            af[i] = *reinterpret_cast<const bf16x8*>(LA + AREG + offA[i]);
        if (st) STAGE_A(tn, 1);
        __builtin_amdgcn_sched_barrier(0);
        __builtin_amdgcn_s_barrier();
        __builtin_amdgcn_sched_barrier(0);
        __builtin_amdgcn_s_setprio(1);
#pragma unroll
        for (int i = 0; i < 4; ++i)
#pragma unroll
            for (int n = 0; n < 4; ++n)
                acc[i][n] = __builtin_amdgcn_mfma_f32_16x16x32_bf16(af[i], bfr[n], acc[i][n], 0, 0, 0);
        __builtin_amdgcn_s_setprio(0);
        __builtin_amdgcn_sched_barrier(0);
        __builtin_amdgcn_s_barrier();
        __builtin_amdgcn_sched_barrier(0);

        // ---- phase (kh1, mhalf1): 4 reads, stage B-kh1(t+1), 16 MFMA, W2
#pragma unroll
        for (int i = 0; i < 4; ++i)
            af[i] = *reinterpret_cast<const bf16x8*>(LA + AREG + offA[4 + i]);
        if (st) STAGE_B(tn, 1);
        __builtin_amdgcn_sched_barrier(0);
        __builtin_amdgcn_s_barrier();
        __builtin_amdgcn_sched_barrier(0);
        __builtin_amdgcn_s_setprio(1);
#pragma unroll
        for (int i = 0; i < 4; ++i)
#pragma unroll
            for (int n = 0; n < 4; ++n)
                acc[4 + i][n] = __builtin_amdgcn_mfma_f32_16x16x32_bf16(af[i], bfr[n], acc[4 + i][n], 0, 0, 0);
        __builtin_amdgcn_s_setprio(0);
        // W2: need next tile's kh0 (newer in flight: A-kh1(t+1), B-kh1(t+1))
        if (t < NT - 1) asm volatile("s_waitcnt vmcnt(4)" ::: "memory");
        __builtin_amdgcn_sched_barrier(0);
        __builtin_amdgcn_s_barrier();
        __builtin_amdgcn_sched_barrier(0);
    }
#undef STAGE_A
#undef STAGE_B

    // epilogue: per-row min over this wave's 64 columns -> cand[row][group]
    const int group = bx * 4 + wn;
    float c2v[4];
#pragma unroll
    for (int n = 0; n < 4; ++n)
        c2v[n] = c2[brow0 + wn * 64 + n * 16 + fr];

#pragma unroll
    for (int mi = 0; mi < 8; ++mi) {
#pragma unroll
        for (int r = 0; r < 4; ++r) {
            unsigned long long bk = ~0ull;
#pragma unroll
            for (int ni = 0; ni < 4; ++ni) {
                const float d2a = c2v[ni] - 2.0f * acc[mi][ni][r];
                const unsigned col = (unsigned)(brow0 + wn * 64 + ni * 16 + fr);
                const unsigned long long key =
                    ((unsigned long long)ord_of_f32(d2a) << 32) | col;
                if (key < bk) bk = key;
            }
#pragma unroll
            for (int ms = 1; ms < 16; ms <<= 1) {
                const unsigned long long o = __shfl_xor(bk, ms, 64);
                if (o < bk) bk = o;
            }
            if (fr == 0) {
                const size_t grow = arow0 + wm * 128 + mi * 16 + fc * 4 + r;
                cand[grow * 64 + group] = bk;
            }
        }
    }
}

// ---------------------------------------------------------------------------
// finalize: verified rounds 2-3, unchanged.
// ---------------------------------------------------------------------------
__global__ __launch_bounds__(256) void finalize(
    const unsigned long long* __restrict__ cand,
    const float* __restrict__ X, const float* __restrict__ C,
    const float* __restrict__ denx, const float* __restrict__ denc,
    const float* __restrict__ x2, const float* __restrict__ c2,
    float* __restrict__ out)
{
    const int w = threadIdx.x >> 6, lane = threadIdx.x & 63;
    const size_t row = (size_t)blockIdx.x * 4 + w;

    const unsigned long long v = cand[row * 64 + lane];
    unsigned long long m = v;
#pragma unroll
    for (int ms = 1; ms < 64; ms <<= 1) {
        const unsigned long long o = __shfl_xor(m, ms, 64);
        if (o < m) m = o;
    }
    const float fmin = f32_of_ord((unsigned)(m >> 32));
    const bool is_cand = f32_of_ord((unsigned)(v >> 32)) <= fmin + EPS_CAND;
    const unsigned long long ball = __ballot(is_cand);

    unsigned win;
    if (__popcll(ball) == 1) {
        win = (unsigned)(m & 0xffffffffu);
    } else {
        const float dxr = denx[row];
        const float x2r = x2[row];
        float xv[16];
#pragma unroll
        for (int j = 0; j < 16; ++j)
            xv[j] = X[row * D_DIM + j * 64 + lane] / dxr;

        float bestd2 = __uint_as_float(0x7f800000u);
        unsigned bwin = 0xffffffffu;
        unsigned long long bb = ball;
        while (bb) {
            const int l = __ffsll((unsigned long long)bb) - 1;
            bb &= bb - 1;
            const unsigned col = (unsigned)(__shfl(v, l, 64) & 0xffffffffu);
            const float dcr = denc[col];
            double s = 0.0;
#pragma unroll
            for (int j = 0; j < 16; ++j) {
                const float cv = C[(size_t)col * D_DIM + j * 64 + lane] / dcr;
                s = fma((double)xv[j], (double)cv, s);
            }
#pragma unroll
            for (int ms = 1; ms < 64; ms <<= 1) s += __shfl_xor(s, ms, 64);
            const float dotf = (float)s;
            const float d2 = (x2r + c2[col]) - 2.0f * dotf;
            if (d2 < bestd2 || (d2 == bestd2 && col < bwin)) {
                bestd2 = d2; bwin = col;
            }
        }
        win = bwin;
    }

    const float4* s4 = reinterpret_cast<const float4*>(C + (size_t)win * D_DIM);
    float4* d4 = reinterpret_cast<float4*>(out + row * D_DIM);
#pragma unroll
    for (int t = 0; t < 4; ++t) d4[t * 64 + lane] = s4[t * 64 + lane];
}

extern "C" void kernel_launch(void* const* d_in, const int* in_sizes, int n_in,
                              void* d_out, int out_size, void* d_ws, size_t ws_size,
                              hipStream_t stream)
{
    (void)in_sizes; (void)n_in; (void)out_size; (void)ws_size;
    const float* X = (const float*)d_in[0];   // [32768,1024] f32
    const float* C = (const float*)d_in[1];   // [4096,1024]  f32
    float* out = (float*)d_out;               // [32768,1024] f32

    char* ws = (char*)d_ws;
    u16* Ahi = (u16*)ws;                                     // 64 MiB
    u16* Alo = Ahi + (size_t)B_ROWS * D_DIM;                 // 64 MiB
    u16* Bhi = Alo + (size_t)B_ROWS * D_DIM;                 //  8 MiB
    u16* Blo = Bhi + (size_t)K_CENT * D_DIM;                 //  8 MiB
    unsigned long long* cand =
        (unsigned long long*)(Blo + (size_t)K_CENT * D_DIM); // 16 MiB
    float* c2   = (float*)(cand + (size_t)B_ROWS * 64);      // 16 KiB
    float* x2   = c2 + K_CENT;                               // 128 KiB
    float* denx = x2 + B_ROWS;                               // 128 KiB
    float* denc = denx + B_ROWS;                             // 16 KiB

    prep_rows<<<B_ROWS, 256, 0, stream>>>(X, Ahi, Alo, x2, denx);
    prep_rows<<<K_CENT, 256, 0, stream>>>(C, Bhi, Blo, c2, denc);
    gemm_cand<<<(B_ROWS / BM) * (K_CENT / BN), 512, 0, stream>>>(
        Ahi, Alo, Bhi, Blo, c2, cand);
    finalize<<<B_ROWS / 4, 256, 0, stream>>>(
        cand, X, C, denx, denc, x2, c2, out);
}